// Round 4
// baseline (428.386 us; speedup 1.0000x reference)
//
#include <hip/hip_runtime.h>
#include <cstdint>
#include <cstddef>

#define H 128
#define PSTRIDE 512   // packed row: [ch | cc | Ufh | Ah], all bf16 x128

typedef __bf16 v8bf __attribute__((ext_vector_type(8)));
typedef __bf16 v4bf __attribute__((ext_vector_type(4)));
typedef float  v4f  __attribute__((ext_vector_type(4)));

__device__ __forceinline__ float ftanh(float x) {
    return 1.f - 2.f / (1.f + __expf(2.f * x));
}
__device__ __forceinline__ float fsigm(float x) {
    return 1.f / (1.f + __expf(-x));
}

struct MatDesc {
    const void*   A;    // bf16 (af32=0) or f32 (af32=1), stride lda
    int           lda;
    int           af32;
    const __bf16* Wb;   // [128,128] bf16 [n][k]
    const float*  bias; // [128] or nullptr
    __bf16*       C;    // bf16 out, stride ldc
    int           ldc;
};
struct MatBatch { MatDesc m[7]; };
struct WPtrs { const float* w[10]; };

// ---------------- prep: wconv (10 mats) + convert ch/cc into P + edge histogram ----------------
__global__ __launch_bounds__(256) void prep_k(WPtrs wp, __bf16* __restrict__ Wb,
                                              const float* __restrict__ chh,
                                              const float* __restrict__ chc,
                                              __bf16* __restrict__ P,
                                              const int* __restrict__ ci,
                                              int* __restrict__ counts,
                                              int MH4, int L) {
    int tid = blockIdx.x * 256 + threadIdx.x;
    if (tid < 40960) {  // 10 * 4096 v4-chunks of weights
        int mat = tid >> 12;
        int off = (tid & 4095) << 2;
        v4f a = *(const v4f*)(wp.w[mat] + off);
        v4bf b;
#pragma unroll
        for (int k = 0; k < 4; ++k) b[k] = (__bf16)a[k];
        *(v4bf*)(Wb + mat * 16384 + off) = b;
        return;
    }
    int i = tid - 40960;
    if (i < MH4) {
        v4f b = ((const v4f*)chh)[i];
        v4f c = ((const v4f*)chc)[i];
        v4bf bb, cb;
#pragma unroll
        for (int k = 0; k < 4; ++k) { bb[k] = (__bf16)b[k]; cb[k] = (__bf16)c[k]; }
        int m = i >> 5;
        int q = (i & 31) << 2;
        __bf16* prow = P + (size_t)m * PSTRIDE + q;
        *(v4bf*)prow = bb;
        *(v4bf*)(prow + H) = cb;
        return;
    }
    int l = i - MH4;
    if (l < L) atomicAdd(&counts[ci[l]], 1);
}

// ---------------- batched GEMM: 1-D grid, tile-grouped XCD swizzle ----------------
// blk -> (mat j, tile t) such that the 7 mats of tile t share XCD (blk%8) and a
// 56-block dispatch window: A-tile rows are read from HBM once, then L2-hit.
__global__ __launch_bounds__(256) void gemm_batch(MatBatch batch, int M, int ntile) {
    const int blk = blockIdx.x;
    const int g = blk / 56;
    const int w = blk % 56;
    const int j = w >> 3;            // mat 0..6
    const int t = (g << 3) | (w & 7);// tile
    if (t >= ntile) return;
    const MatDesc d = batch.m[j];
    __shared__ __bf16 wlds[H][H + 8];

    for (int tt = threadIdx.x; tt < 2048; tt += 256) {
        int n = tt >> 4;
        int k = (tt & 15) << 3;
        *(v8bf*)&wlds[n][k] = *(const v8bf*)(d.Wb + n * H + k);
    }
    __syncthreads();

    const int wave = threadIdx.x >> 6;
    const int lane = threadIdx.x & 63;
    const int quad = lane >> 4;
    const int l16  = lane & 15;
    const int r0   = t * 128 + wave * 32;

    // clamp row loads (x_emb is exactly M rows); rows >= M produce garbage, masked at store
    int ra = r0 + l16;      if (ra > M - 1) ra = M - 1;
    int rb = r0 + 16 + l16; if (rb > M - 1) rb = M - 1;

    v8bf a0[4], a1[4];
    if (d.af32) {
        const float* A = (const float*)d.A;
        const float* p0 = A + (size_t)ra * d.lda + quad * 8;
        const float* p1 = A + (size_t)rb * d.lda + quad * 8;
#pragma unroll
        for (int k0 = 0; k0 < 4; ++k0) {
            v4f x0a = *(const v4f*)(p0 + k0 * 32);
            v4f x0b = *(const v4f*)(p0 + k0 * 32 + 4);
            v4f x1a = *(const v4f*)(p1 + k0 * 32);
            v4f x1b = *(const v4f*)(p1 + k0 * 32 + 4);
            v8bf t0, t1;
#pragma unroll
            for (int k = 0; k < 4; ++k) {
                t0[k] = (__bf16)x0a[k]; t0[k + 4] = (__bf16)x0b[k];
                t1[k] = (__bf16)x1a[k]; t1[k + 4] = (__bf16)x1b[k];
            }
            a0[k0] = t0; a1[k0] = t1;
        }
    } else {
        const __bf16* A = (const __bf16*)d.A;
        const __bf16* p0 = A + (size_t)ra * d.lda + quad * 8;
        const __bf16* p1 = A + (size_t)rb * d.lda + quad * 8;
#pragma unroll
        for (int k0 = 0; k0 < 4; ++k0) {
            a0[k0] = *(const v8bf*)(p0 + k0 * 32);
            a1[k0] = *(const v8bf*)(p1 + k0 * 32);
        }
    }

    v4f acc0[8], acc1[8];
#pragma unroll
    for (int nt = 0; nt < 8; ++nt) {
        acc0[nt] = (v4f){0.f, 0.f, 0.f, 0.f};
        acc1[nt] = (v4f){0.f, 0.f, 0.f, 0.f};
    }

#pragma unroll
    for (int k0 = 0; k0 < 4; ++k0) {
#pragma unroll
        for (int nt = 0; nt < 8; ++nt) {
            v8bf b = *(const v8bf*)(&wlds[nt * 16 + l16][k0 * 32 + quad * 8]);
            acc0[nt] = __builtin_amdgcn_mfma_f32_16x16x32_bf16(a0[k0], b, acc0[nt], 0, 0, 0);
            acc1[nt] = __builtin_amdgcn_mfma_f32_16x16x32_bf16(a1[k0], b, acc1[nt], 0, 0, 0);
        }
    }

#pragma unroll
    for (int nt = 0; nt < 8; ++nt) {
        int n = nt * 16 + l16;
        float bia = d.bias ? d.bias[n] : 0.f;
#pragma unroll
        for (int r = 0; r < 4; ++r) {
            int m0 = r0 + quad * 4 + r;
            int m1 = m0 + 16;
            if (m0 < M) d.C[(size_t)m0 * d.ldc + n] = (__bf16)(acc0[nt][r] + bia);
            if (m1 < M) d.C[(size_t)m1 * d.ldc + n] = (__bf16)(acc1[nt][r] + bia);
        }
    }
}

// ---------------- scans ----------------
__global__ __launch_bounds__(1024) void scan_local(const int* __restrict__ counts,
                                                   int* __restrict__ excl,
                                                   int* __restrict__ bsums, int M) {
    __shared__ int s[1024];
    int tid = threadIdx.x;
    int idx = blockIdx.x * 1024 + tid;
    int v = (idx < M) ? counts[idx] : 0;
    s[tid] = v;
    __syncthreads();
    for (int off = 1; off < 1024; off <<= 1) {
        int t = (tid >= off) ? s[tid - off] : 0;
        __syncthreads();
        s[tid] += t;
        __syncthreads();
    }
    if (idx < M) excl[idx] = s[tid] - v;
    if (tid == 1023) bsums[blockIdx.x] = s[1023];
}

__global__ __launch_bounds__(1024) void scan_fused(int* __restrict__ rowptr,
                                                   int* __restrict__ cursor,
                                                   const int* __restrict__ bsums,
                                                   const int* __restrict__ counts,
                                                   int M, int nb) {
    __shared__ int s[1024];
    int t = threadIdx.x, b = blockIdx.x;
    int v = (t < nb) ? bsums[t] : 0;
    s[t] = v;
    __syncthreads();
    for (int off = 1; off < 1024; off <<= 1) {
        int tt = (t >= off) ? s[t - off] : 0;
        __syncthreads();
        s[t] += tt;
        __syncthreads();
    }
    int boff = (b == 0) ? 0 : s[b - 1];
    int idx = b * 1024 + t;
    if (idx < M) {
        int val = rowptr[idx] + boff;
        rowptr[idx] = val;
        cursor[idx] = val;
        if (idx == M - 1) rowptr[M] = val + counts[M - 1];
    }
}

// ---------------- scatter: CSR payload = child index ----------------
__global__ __launch_bounds__(256) void scatter_k(const int* __restrict__ ci,
                                                 const int* __restrict__ chi,
                                                 int* __restrict__ cursor,
                                                 int* __restrict__ payload, int L) {
    int l = blockIdx.x * 256 + threadIdx.x;
    if (l < L) {
        int pos = atomicAdd(&cursor[ci[l]], 1);
        payload[pos] = chi[l];
    }
}

// ---------------- fused attention + segment reduce, SINGLE PASS, 2-edge unrolled ----------------
// 32 lanes/segment, 4 feats/lane. Bx[m]/Wfx[m] are per-segment register broadcasts;
// per edge we gather one packed 1KB P-row (ch|cc|Ufh|Ah) - all 4 sections same DRAM page.
// 2x unroll doubles outstanding gathers + interleaves two independent butterfly chains.
__global__ __launch_bounds__(256) void segment_fused(const int* __restrict__ rowptr,
                                                     const int* __restrict__ payload,
                                                     const float* __restrict__ vw,
                                                     const __bf16* __restrict__ Bx,
                                                     const __bf16* __restrict__ Wfx,
                                                     const __bf16* __restrict__ P,
                                                     __bf16* __restrict__ hhat,
                                                     float* __restrict__ sumfc, int M) {
    const int wl   = threadIdx.x & 63;
    const int half = wl & 32;
    const int l32  = wl & 31;
    const int m = blockIdx.x * 8 + (threadIdx.x >> 5);
    if (m >= M) return;
    const int start = rowptr[m];
    const int deg   = rowptr[m + 1] - start;
    const int h = l32 << 2;

    v4bf bx4 = *(const v4bf*)(Bx + (m << 7) + h);
    v4bf wf4 = *(const v4bf*)(Wfx + (m << 7) + h);
    v4f  vv  = *(const v4f*)(vw + h);
    float bxf[4], wff[4];
#pragma unroll
    for (int k = 0; k < 4; ++k) { bxf[k] = (float)bx4[k]; wff[k] = (float)wf4[k]; }

    // batch payload loads (1 per lane per 32 edges)
    int pl0 = (l32 < deg) ? payload[start + l32] : 0;
    int pl1 = (32 + l32 < deg) ? payload[start + 32 + l32] : 0;

    float denom = 0.f;
    float acch[4] = {0.f, 0.f, 0.f, 0.f};
    float accf[4] = {0.f, 0.f, 0.f, 0.f};

    const int jcap = deg < 64 ? deg : 64;
    int j = 0;
    for (; j + 2 <= jcap; j += 2) {
        int cj0 = __shfl((j & 32) ? pl1 : pl0, half | (j & 31), 64);
        int cj1 = __shfl((j & 32) ? pl1 : pl0, half | ((j + 1) & 31), 64);
        const __bf16* pb0 = P + ((size_t)cj0 << 9) + h;
        const __bf16* pb1 = P + ((size_t)cj1 << 9) + h;
        v4bf h40 = *(const v4bf*)pb0;
        v4bf c40 = *(const v4bf*)(pb0 + H);
        v4bf u40 = *(const v4bf*)(pb0 + 2 * H);
        v4bf a40 = *(const v4bf*)(pb0 + 3 * H);
        v4bf h41 = *(const v4bf*)pb1;
        v4bf c41 = *(const v4bf*)(pb1 + H);
        v4bf u41 = *(const v4bf*)(pb1 + 2 * H);
        v4bf a41 = *(const v4bf*)(pb1 + 3 * H);
        float s0 = 0.f, s1 = 0.f;
#pragma unroll
        for (int k = 0; k < 4; ++k) {
            s0 += ftanh((float)a40[k] + bxf[k]) * vv[k];
            s1 += ftanh((float)a41[k] + bxf[k]) * vv[k];
        }
        s0 += __shfl_xor(s0, 1);  s1 += __shfl_xor(s1, 1);
        s0 += __shfl_xor(s0, 2);  s1 += __shfl_xor(s1, 2);
        s0 += __shfl_xor(s0, 4);  s1 += __shfl_xor(s1, 4);
        s0 += __shfl_xor(s0, 8);  s1 += __shfl_xor(s1, 8);
        s0 += __shfl_xor(s0, 16); s1 += __shfl_xor(s1, 16);
        float ex0 = __expf(s0);
        float ex1 = __expf(s1);
        denom += ex0 + ex1;
#pragma unroll
        for (int k = 0; k < 4; ++k) {
            acch[k] = fmaf(ex0, (float)h40[k], acch[k]);
            acch[k] = fmaf(ex1, (float)h41[k], acch[k]);
            accf[k] += fsigm(wff[k] + (float)u40[k]) * (float)c40[k];
            accf[k] += fsigm(wff[k] + (float)u41[k]) * (float)c41[k];
        }
    }
    for (; j < jcap; ++j) {
        int cj = __shfl((j & 32) ? pl1 : pl0, half | (j & 31), 64);
        const __bf16* pb = P + ((size_t)cj << 9) + h;
        v4bf h4 = *(const v4bf*)pb;
        v4bf c4 = *(const v4bf*)(pb + H);
        v4bf u4 = *(const v4bf*)(pb + 2 * H);
        v4bf a4 = *(const v4bf*)(pb + 3 * H);
        float s = 0.f;
#pragma unroll
        for (int k = 0; k < 4; ++k) s += ftanh((float)a4[k] + bxf[k]) * vv[k];
        s += __shfl_xor(s, 1);
        s += __shfl_xor(s, 2);
        s += __shfl_xor(s, 4);
        s += __shfl_xor(s, 8);
        s += __shfl_xor(s, 16);
        float ex = __expf(s);
        denom += ex;
#pragma unroll
        for (int k = 0; k < 4; ++k) {
            acch[k] = fmaf(ex, (float)h4[k], acch[k]);
            accf[k] += fsigm(wff[k] + (float)u4[k]) * (float)c4[k];
        }
    }
    // rare tail (deg > 64)
    for (int jj = 64; jj < deg; ++jj) {
        int cj = payload[start + jj];
        const __bf16* pb = P + ((size_t)cj << 9) + h;
        v4bf h4 = *(const v4bf*)pb;
        v4bf c4 = *(const v4bf*)(pb + H);
        v4bf u4 = *(const v4bf*)(pb + 2 * H);
        v4bf a4 = *(const v4bf*)(pb + 3 * H);
        float s = 0.f;
#pragma unroll
        for (int k = 0; k < 4; ++k) s += ftanh((float)a4[k] + bxf[k]) * vv[k];
        s += __shfl_xor(s, 1);
        s += __shfl_xor(s, 2);
        s += __shfl_xor(s, 4);
        s += __shfl_xor(s, 8);
        s += __shfl_xor(s, 16);
        float ex = __expf(s);
        denom += ex;
#pragma unroll
        for (int k = 0; k < 4; ++k) {
            acch[k] = fmaf(ex, (float)h4[k], acch[k]);
            accf[k] += fsigm(wff[k] + (float)u4[k]) * (float)c4[k];
        }
    }

    float inv = 1.f / (denom + 1e-9f);
    v4bf hb;
    v4f sf;
#pragma unroll
    for (int k = 0; k < 4; ++k) { hb[k] = (__bf16)(acch[k] * inv); sf[k] = accf[k]; }
    *(v4bf*)(hhat + (size_t)m * H + h) = hb;
    *(v4f*)(sumfc + (size_t)m * H + h) = sf;
}

// ---------------- fused gemm2 (hhat @ {Ui,Uc,Uo}) + LSTM epilogue, NO LDS ----------------
// Weights (96 KB total) are L2/L3-resident; loading B-frags from global keeps
// occupancy high (no LDS cap, no barriers).
__global__ __launch_bounds__(256) void gemm_final(const __bf16* __restrict__ hhat,
                                                  const __bf16* __restrict__ Ui,
                                                  const __bf16* __restrict__ Uc,
                                                  const __bf16* __restrict__ Uo,
                                                  const __bf16* __restrict__ Xi,
                                                  const __bf16* __restrict__ Xc,
                                                  const __bf16* __restrict__ Xo,
                                                  const float* __restrict__ sumfc,
                                                  float* __restrict__ out, int M, int MH) {
    const int wave = threadIdx.x >> 6;
    const int lane = threadIdx.x & 63;
    const int quad = lane >> 4;
    const int l16  = lane & 15;
    const int r0   = blockIdx.x * 128 + wave * 32;

    // hhat is Mpad-padded workspace; rows >= M are garbage but masked at store
    const __bf16* p0 = hhat + (size_t)(r0 + l16) * H + quad * 8;
    const __bf16* p1 = hhat + (size_t)(r0 + 16 + l16) * H + quad * 8;
    v8bf a0[4], a1[4];
#pragma unroll
    for (int k0 = 0; k0 < 4; ++k0) {
        a0[k0] = *(const v8bf*)(p0 + k0 * 32);
        a1[k0] = *(const v8bf*)(p1 + k0 * 32);
    }

#pragma unroll
    for (int nt = 0; nt < 8; ++nt) {
        const int boff = (nt * 16 + l16) * H + quad * 8;
        v4f ai0 = (v4f){0.f, 0.f, 0.f, 0.f}, ai1 = ai0;
        v4f ac0 = ai0, ac1 = ai0, ao0 = ai0, ao1 = ai0;
#pragma unroll
        for (int k0 = 0; k0 < 4; ++k0) {
            v8bf bi = *(const v8bf*)(Ui + boff + k0 * 32);
            v8bf bc = *(const v8bf*)(Uc + boff + k0 * 32);
            v8bf bo = *(const v8bf*)(Uo + boff + k0 * 32);
            ai0 = __builtin_amdgcn_mfma_f32_16x16x32_bf16(a0[k0], bi, ai0, 0, 0, 0);
            ai1 = __builtin_amdgcn_mfma_f32_16x16x32_bf16(a1[k0], bi, ai1, 0, 0, 0);
            ac0 = __builtin_amdgcn_mfma_f32_16x16x32_bf16(a0[k0], bc, ac0, 0, 0, 0);
            ac1 = __builtin_amdgcn_mfma_f32_16x16x32_bf16(a1[k0], bc, ac1, 0, 0, 0);
            ao0 = __builtin_amdgcn_mfma_f32_16x16x32_bf16(a0[k0], bo, ao0, 0, 0, 0);
            ao1 = __builtin_amdgcn_mfma_f32_16x16x32_bf16(a1[k0], bo, ao1, 0, 0, 0);
        }
        int n = nt * 16 + l16;
#pragma unroll
        for (int r = 0; r < 4; ++r) {
            int m0 = r0 + quad * 4 + r;
            if (m0 < M) {
                size_t idx = (size_t)m0 * H + n;
                float ig = fsigm((float)Xi[idx] + ai0[r]);
                float ct = ftanh((float)Xc[idx] + ac0[r]);
                float og = fsigm((float)Xo[idx] + ao0[r]);
                float c = ig * ct + sumfc[idx];
                out[idx] = og * ftanh(c);
                out[MH + idx] = c;
            }
            int m1 = m0 + 16;
            if (m1 < M) {
                size_t idx = (size_t)m1 * H + n;
                float ig = fsigm((float)Xi[idx] + ai1[r]);
                float ct = ftanh((float)Xc[idx] + ac1[r]);
                float og = fsigm((float)Xo[idx] + ao1[r]);
                float c = ig * ct + sumfc[idx];
                out[idx] = og * ftanh(c);
                out[MH + idx] = c;
            }
        }
    }
}

extern "C" void kernel_launch(void* const* d_in, const int* in_sizes, int n_in,
                              void* d_out, int out_size, void* d_ws, size_t ws_size,
                              hipStream_t stream) {
    const float* x_emb   = (const float*)d_in[0];
    const float* child_h = (const float*)d_in[1];
    const float* child_c = (const float*)d_in[2];
    const int*   ci      = (const int*)d_in[3];
    const int*   chi     = (const int*)d_in[4];
    const float* Wi_b = (const float*)d_in[15];
    const float* Wf_b = (const float*)d_in[16];
    const float* Wo_b = (const float*)d_in[17];
    const float* Wc_b = (const float*)d_in[18];
    const float* Wa_b = (const float*)d_in[19];
    const float* vw   = (const float*)d_in[20];

    const int M    = in_sizes[0] / H;
    const int L    = in_sizes[3];
    const int Mpad = (M + 127) & ~127;
    const int MH   = M * H;
    const int MH4  = MH / 4;

    char* p = (char*)d_ws;
    auto alloc = [&](size_t bytes) {
        char* r = p;
        p += (bytes + 255) & ~(size_t)255;
        return (void*)r;
    };
    size_t bfbytes = (size_t)Mpad * H * sizeof(__bf16);
    __bf16* P      = (__bf16*)alloc((size_t)Mpad * PSTRIDE * sizeof(__bf16));
    __bf16* hhat16 = (__bf16*)alloc(bfbytes);
    __bf16* Bx16   = (__bf16*)alloc(bfbytes);
    __bf16* Wfx16  = (__bf16*)alloc(bfbytes);
    __bf16* Xi16   = (__bf16*)alloc(bfbytes);
    __bf16* Xc16   = (__bf16*)alloc(bfbytes);
    __bf16* Xo16   = (__bf16*)alloc(bfbytes);
    __bf16* Wb     = (__bf16*)alloc(10 * 16384 * sizeof(__bf16));
    float* sumfc   = (float*)alloc((size_t)MH * 4);
    int*   payload = (int*)alloc((size_t)L * 4);
    int*   counts  = (int*)alloc((size_t)M * 4);
    int*   rowptr  = (int*)alloc((size_t)(M + 1) * 4);
    int*   cursor  = (int*)alloc((size_t)M * 4);
    int*   bsums   = (int*)alloc(1024 * 4);

    hipMemsetAsync(counts, 0, (size_t)M * 4, stream);

    WPtrs wp;
    for (int k = 0; k < 10; ++k) wp.w[k] = (const float*)d_in[5 + k];
    int prep_items = 40960 + MH4 + L;
    prep_k<<<(prep_items + 255) / 256, 256, 0, stream>>>(wp, Wb, child_h, child_c,
                                                         P, ci, counts, MH4, L);

    const __bf16* Wi = Wb + 0 * 16384;
    const __bf16* Ui = Wb + 1 * 16384;
    const __bf16* Wf = Wb + 2 * 16384;
    const __bf16* Uf = Wb + 3 * 16384;
    const __bf16* Wo = Wb + 4 * 16384;
    const __bf16* Uo = Wb + 5 * 16384;
    const __bf16* Wc = Wb + 6 * 16384;
    const __bf16* Uc = Wb + 7 * 16384;
    const __bf16* Wa = Wb + 8 * 16384;
    const __bf16* Ua = Wb + 9 * 16384;

    MatBatch ba{};
    ba.m[0] = MatDesc{P,     PSTRIDE, 0, Wa, Wa_b,    P + 3 * H, PSTRIDE}; // Ah -> P sec3
    ba.m[1] = MatDesc{x_emb, H,       1, Ua, nullptr, Bx16,      H};       // Bx
    ba.m[2] = MatDesc{x_emb, H,       1, Wf, Wf_b,    Wfx16,     H};       // Wfx
    ba.m[3] = MatDesc{P,     PSTRIDE, 0, Uf, nullptr, P + 2 * H, PSTRIDE}; // Ufh -> P sec2
    ba.m[4] = MatDesc{x_emb, H,       1, Wi, Wi_b,    Xi16,      H};
    ba.m[5] = MatDesc{x_emb, H,       1, Wc, Wc_b,    Xc16,      H};
    ba.m[6] = MatDesc{x_emb, H,       1, Wo, Wo_b,    Xo16,      H};
    const int ntile = Mpad / 128;
    const int ntile8 = (ntile + 7) & ~7;
    gemm_batch<<<7 * ntile8, 256, 0, stream>>>(ba, M, ntile);

    int nb = (M + 1023) / 1024;
    scan_local<<<nb, 1024, 0, stream>>>(counts, rowptr, bsums, M);
    scan_fused<<<nb, 1024, 0, stream>>>(rowptr, cursor, bsums, counts, M, nb);

    scatter_k<<<(L + 255) / 256, 256, 0, stream>>>(ci, chi, cursor, payload, L);

    segment_fused<<<(M + 7) / 8, 256, 0, stream>>>(rowptr, payload, vw, Bx16, Wfx16, P,
                                                   hhat16, sumfc, M);

    gemm_final<<<Mpad / 128, 256, 0, stream>>>(hhat16, Ui, Uc, Uo, Xi16, Xc16, Xo16,
                                               sumfc, (float*)d_out, M, MH);
}

// Round 5
// 412.423 us; speedup vs baseline: 1.0387x; 1.0387x over previous
//
#include <hip/hip_runtime.h>
#include <cstdint>
#include <cstddef>

#define H 128
#define PSTRIDE 512   // packed row, interleaved by feature-quad: q*16 + [ch4|cc4|uf4|ah4]

typedef __bf16 v8bf __attribute__((ext_vector_type(8)));
typedef __bf16 v4bf __attribute__((ext_vector_type(4)));
typedef float  v4f  __attribute__((ext_vector_type(4)));

__device__ __forceinline__ float ftanh(float x) {
    return 1.f - 2.f / (1.f + __expf(2.f * x));
}
__device__ __forceinline__ float fsigm(float x) {
    return 1.f / (1.f + __expf(-x));
}

// 32-lane sum reduce: 4 DPP adds (VALU pipe, cheap) + 1 ds_swizzle xor16.
// All 32 lanes of each half end with the full sum. Halves are independent.
__device__ __forceinline__ float red32(float s) {
    int x;
    x = __builtin_amdgcn_update_dpp(0, __float_as_int(s), 0xB1, 0xF, 0xF, true);  // quad_perm [1,0,3,2] = xor1
    s += __int_as_float(x);
    x = __builtin_amdgcn_update_dpp(0, __float_as_int(s), 0x4E, 0xF, 0xF, true);  // quad_perm [2,3,0,1] = xor2
    s += __int_as_float(x);
    x = __builtin_amdgcn_update_dpp(0, __float_as_int(s), 0x141, 0xF, 0xF, true); // row_half_mirror (8-lane)
    s += __int_as_float(x);
    x = __builtin_amdgcn_update_dpp(0, __float_as_int(s), 0x140, 0xF, 0xF, true); // row_mirror (16-lane)
    s += __int_as_float(x);
    x = __builtin_amdgcn_ds_swizzle(__float_as_int(s), 0x401F);                   // xor16 within 32
    return s + __int_as_float(x);
}

struct MatDesc {
    const __bf16* A;    // bf16 A, stride lda
    int           lda;
    const __bf16* Wb;   // [128,128] bf16 [n][k]
    const float*  bias; // [128] or nullptr
    __bf16*       C;    // out base (contig if psec<0, else P-interleaved)
    int           ldc;
    int           psec; // -1 = contiguous; 2 = Ufh slot, 3 = Ah slot in P rows
};
struct MatBatch { MatDesc m[7]; };
struct WPtrs { const float* w[10]; };

// ---------------- prep: wconv (10 mats) + convert x/ch/cc + edge histogram ----------------
__global__ __launch_bounds__(256) void prep_k(WPtrs wp, __bf16* __restrict__ Wb,
                                              const float* __restrict__ x,
                                              const float* __restrict__ chh,
                                              const float* __restrict__ chc,
                                              __bf16* __restrict__ xe,
                                              __bf16* __restrict__ chA,
                                              __bf16* __restrict__ P,
                                              const int* __restrict__ ci,
                                              int* __restrict__ counts,
                                              int MH4, int L) {
    int tid = blockIdx.x * 256 + threadIdx.x;
    if (tid < 40960) {  // 10 * 4096 v4-chunks of weights
        int mat = tid >> 12;
        int off = (tid & 4095) << 2;
        v4f a = *(const v4f*)(wp.w[mat] + off);
        v4bf b;
#pragma unroll
        for (int k = 0; k < 4; ++k) b[k] = (__bf16)a[k];
        *(v4bf*)(Wb + mat * 16384 + off) = b;
        return;
    }
    int i = tid - 40960;
    if (i < MH4) {
        v4f a = ((const v4f*)x)[i];
        v4f b = ((const v4f*)chh)[i];
        v4f c = ((const v4f*)chc)[i];
        v4bf ab, bb, cb;
#pragma unroll
        for (int k = 0; k < 4; ++k) {
            ab[k] = (__bf16)a[k]; bb[k] = (__bf16)b[k]; cb[k] = (__bf16)c[k];
        }
        ((v4bf*)xe)[i] = ab;
        ((v4bf*)chA)[i] = bb;
        int m = i >> 5;
        int q = i & 31;
        __bf16* prow = P + (size_t)m * PSTRIDE + (q << 4);
        *(v4bf*)prow = bb;        // ch quad
        *(v4bf*)(prow + 4) = cb;  // cc quad
        return;
    }
    int l = i - MH4;
    if (l < L) atomicAdd(&counts[ci[l]], 1);
}

// ---------------- batched GEMM: 1-D grid, tile-grouped XCD swizzle ----------------
// blk -> (mat j, tile t) such that the 7 mats of tile t share XCD (blk%8) and a
// 56-block dispatch window: A-tile rows are read from HBM once, then L2-hit.
__global__ __launch_bounds__(256) void gemm_batch(MatBatch batch, int M, int ntile) {
    const int blk = blockIdx.x;
    const int g = blk / 56;
    const int w = blk % 56;
    const int j = w >> 3;             // mat 0..6
    const int t = (g << 3) | (w & 7); // tile
    if (t >= ntile) return;
    const MatDesc d = batch.m[j];
    __shared__ __bf16 wlds[H][H + 8];

    for (int tt = threadIdx.x; tt < 2048; tt += 256) {
        int n = tt >> 4;
        int k = (tt & 15) << 3;
        *(v8bf*)&wlds[n][k] = *(const v8bf*)(d.Wb + n * H + k);
    }
    __syncthreads();

    const int wave = threadIdx.x >> 6;
    const int lane = threadIdx.x & 63;
    const int quad = lane >> 4;
    const int l16  = lane & 15;
    const int r0   = t * 128 + wave * 32;

    int ra = r0 + l16;      if (ra > M - 1) ra = M - 1;
    int rb = r0 + 16 + l16; if (rb > M - 1) rb = M - 1;

    const __bf16* p0 = d.A + (size_t)ra * d.lda + quad * 8;
    const __bf16* p1 = d.A + (size_t)rb * d.lda + quad * 8;
    v8bf a0[4], a1[4];
#pragma unroll
    for (int k0 = 0; k0 < 4; ++k0) {
        a0[k0] = *(const v8bf*)(p0 + k0 * 32);
        a1[k0] = *(const v8bf*)(p1 + k0 * 32);
    }

    v4f acc0[8], acc1[8];
#pragma unroll
    for (int nt = 0; nt < 8; ++nt) {
        acc0[nt] = (v4f){0.f, 0.f, 0.f, 0.f};
        acc1[nt] = (v4f){0.f, 0.f, 0.f, 0.f};
    }

#pragma unroll
    for (int k0 = 0; k0 < 4; ++k0) {
#pragma unroll
        for (int nt = 0; nt < 8; ++nt) {
            v8bf b = *(const v8bf*)(&wlds[nt * 16 + l16][k0 * 32 + quad * 8]);
            acc0[nt] = __builtin_amdgcn_mfma_f32_16x16x32_bf16(a0[k0], b, acc0[nt], 0, 0, 0);
            acc1[nt] = __builtin_amdgcn_mfma_f32_16x16x32_bf16(a1[k0], b, acc1[nt], 0, 0, 0);
        }
    }

    if (d.psec >= 0) {
        // interleaved store into P rows: elem (m,n) -> m*512 + (n>>2)*16 + psec*4 + (n&3)
        const int so = d.psec << 2;
#pragma unroll
        for (int nt = 0; nt < 8; ++nt) {
            int n = nt * 16 + l16;
            float bia = d.bias ? d.bias[n] : 0.f;
            size_t col = ((size_t)(n >> 2) << 4) + so + (n & 3);
#pragma unroll
            for (int r = 0; r < 4; ++r) {
                int m0 = r0 + quad * 4 + r;
                int m1 = m0 + 16;
                if (m0 < M) d.C[(size_t)m0 * PSTRIDE + col] = (__bf16)(acc0[nt][r] + bia);
                if (m1 < M) d.C[(size_t)m1 * PSTRIDE + col] = (__bf16)(acc1[nt][r] + bia);
            }
        }
    } else {
#pragma unroll
        for (int nt = 0; nt < 8; ++nt) {
            int n = nt * 16 + l16;
            float bia = d.bias ? d.bias[n] : 0.f;
#pragma unroll
            for (int r = 0; r < 4; ++r) {
                int m0 = r0 + quad * 4 + r;
                int m1 = m0 + 16;
                if (m0 < M) d.C[(size_t)m0 * d.ldc + n] = (__bf16)(acc0[nt][r] + bia);
                if (m1 < M) d.C[(size_t)m1 * d.ldc + n] = (__bf16)(acc1[nt][r] + bia);
            }
        }
    }
}

// ---------------- scans ----------------
__global__ __launch_bounds__(1024) void scan_local(const int* __restrict__ counts,
                                                   int* __restrict__ excl,
                                                   int* __restrict__ bsums, int M) {
    __shared__ int s[1024];
    int tid = threadIdx.x;
    int idx = blockIdx.x * 1024 + tid;
    int v = (idx < M) ? counts[idx] : 0;
    s[tid] = v;
    __syncthreads();
    for (int off = 1; off < 1024; off <<= 1) {
        int t = (tid >= off) ? s[tid - off] : 0;
        __syncthreads();
        s[tid] += t;
        __syncthreads();
    }
    if (idx < M) excl[idx] = s[tid] - v;
    if (tid == 1023) bsums[blockIdx.x] = s[1023];
}

__global__ __launch_bounds__(1024) void scan_fused(int* __restrict__ rowptr,
                                                   int* __restrict__ cursor,
                                                   const int* __restrict__ bsums,
                                                   const int* __restrict__ counts,
                                                   int M, int nb) {
    __shared__ int s[1024];
    int t = threadIdx.x, b = blockIdx.x;
    int v = (t < nb) ? bsums[t] : 0;
    s[t] = v;
    __syncthreads();
    for (int off = 1; off < 1024; off <<= 1) {
        int tt = (t >= off) ? s[t - off] : 0;
        __syncthreads();
        s[t] += tt;
        __syncthreads();
    }
    int boff = (b == 0) ? 0 : s[b - 1];
    int idx = b * 1024 + t;
    if (idx < M) {
        int val = rowptr[idx] + boff;
        rowptr[idx] = val;
        cursor[idx] = val;
        if (idx == M - 1) rowptr[M] = val + counts[M - 1];
    }
}

// ---------------- scatter: CSR payload = child index ----------------
__global__ __launch_bounds__(256) void scatter_k(const int* __restrict__ ci,
                                                 const int* __restrict__ chi,
                                                 int* __restrict__ cursor,
                                                 int* __restrict__ payload, int L) {
    int l = blockIdx.x * 256 + threadIdx.x;
    if (l < L) {
        int pos = atomicAdd(&cursor[ci[l]], 1);
        payload[pos] = chi[l];
    }
}

// ---------------- fused attention + segment reduce, SINGLE PASS ----------------
// 32 lanes/segment, 4 feats/lane. Per edge: ONE 32B interleaved P read (2 x b128),
// score reduce via 4 DPP adds + 1 ds_swizzle (short serial chain).
__global__ __launch_bounds__(128) void segment_fused(const int* __restrict__ rowptr,
                                                     const int* __restrict__ payload,
                                                     const float* __restrict__ vw,
                                                     const __bf16* __restrict__ Bx,
                                                     const __bf16* __restrict__ Wfx,
                                                     const __bf16* __restrict__ P,
                                                     __bf16* __restrict__ hhat,
                                                     float* __restrict__ sumfc, int M) {
    const int wl   = threadIdx.x & 63;
    const int half = wl & 32;
    const int l32  = wl & 31;
    const int m = blockIdx.x * 4 + (threadIdx.x >> 5);
    if (m >= M) return;
    const int start = rowptr[m];
    const int deg   = rowptr[m + 1] - start;
    const int h   = l32 << 2;
    const int q16 = l32 << 4;

    v4bf bx4 = *(const v4bf*)(Bx + (m << 7) + h);
    v4bf wf4 = *(const v4bf*)(Wfx + (m << 7) + h);
    v4f  vv  = *(const v4f*)(vw + h);
    float bxf[4], wff[4];
#pragma unroll
    for (int k = 0; k < 4; ++k) { bxf[k] = (float)bx4[k]; wff[k] = (float)wf4[k]; }

    // batch payload loads (1 per lane per 32 edges)
    int pl0 = (l32 < deg) ? payload[start + l32] : 0;
    int pl1 = (32 + l32 < deg) ? payload[start + 32 + l32] : 0;

    float denom = 0.f;
    float acch[4] = {0.f, 0.f, 0.f, 0.f};
    float accf[4] = {0.f, 0.f, 0.f, 0.f};

    const int jcap = deg < 64 ? deg : 64;
    for (int j = 0; j < jcap; ++j) {
        int cj = __shfl((j & 32) ? pl1 : pl0, half | (j & 31), 64);
        const __bf16* pb = P + ((size_t)cj << 9) + q16;
        v8bf x0 = *(const v8bf*)pb;        // ch0-3 | cc0-3
        v8bf x1 = *(const v8bf*)(pb + 8);  // uf0-3 | ah0-3
        float s = 0.f;
#pragma unroll
        for (int k = 0; k < 4; ++k) s += ftanh((float)x1[4 + k] + bxf[k]) * vv[k];
        s = red32(s);
        float ex = __expf(s);
        denom += ex;
#pragma unroll
        for (int k = 0; k < 4; ++k) {
            acch[k] = fmaf(ex, (float)x0[k], acch[k]);
            accf[k] += fsigm(wff[k] + (float)x1[k]) * (float)x0[4 + k];
        }
    }
    // rare tail (deg > 64)
    for (int j = 64; j < deg; ++j) {
        int cj = payload[start + j];
        const __bf16* pb = P + ((size_t)cj << 9) + q16;
        v8bf x0 = *(const v8bf*)pb;
        v8bf x1 = *(const v8bf*)(pb + 8);
        float s = 0.f;
#pragma unroll
        for (int k = 0; k < 4; ++k) s += ftanh((float)x1[4 + k] + bxf[k]) * vv[k];
        s = red32(s);
        float ex = __expf(s);
        denom += ex;
#pragma unroll
        for (int k = 0; k < 4; ++k) {
            acch[k] = fmaf(ex, (float)x0[k], acch[k]);
            accf[k] += fsigm(wff[k] + (float)x1[k]) * (float)x0[4 + k];
        }
    }

    float inv = 1.f / (denom + 1e-9f);
    v4bf hb;
    v4f sf;
#pragma unroll
    for (int k = 0; k < 4; ++k) { hb[k] = (__bf16)(acch[k] * inv); sf[k] = accf[k]; }
    *(v4bf*)(hhat + (size_t)m * H + h) = hb;
    *(v4f*)(sumfc + (size_t)m * H + h) = sf;
}

// ---------------- fused gemm2 (hhat @ {Ui,Uc,Uo}) + LSTM epilogue, NO LDS ----------------
// Weights (96 KB total) are L2/L3-resident; loading B-frags from global keeps
// occupancy high (no LDS cap, no barriers).
__global__ __launch_bounds__(256) void gemm_final(const __bf16* __restrict__ hhat,
                                                  const __bf16* __restrict__ Ui,
                                                  const __bf16* __restrict__ Uc,
                                                  const __bf16* __restrict__ Uo,
                                                  const __bf16* __restrict__ Xi,
                                                  const __bf16* __restrict__ Xc,
                                                  const __bf16* __restrict__ Xo,
                                                  const float* __restrict__ sumfc,
                                                  float* __restrict__ out, int M, int MH) {
    const int wave = threadIdx.x >> 6;
    const int lane = threadIdx.x & 63;
    const int quad = lane >> 4;
    const int l16  = lane & 15;
    const int r0   = blockIdx.x * 128 + wave * 32;

    // hhat is Mpad-padded workspace; rows >= M are garbage but masked at store
    const __bf16* p0 = hhat + (size_t)(r0 + l16) * H + quad * 8;
    const __bf16* p1 = hhat + (size_t)(r0 + 16 + l16) * H + quad * 8;
    v8bf a0[4], a1[4];
#pragma unroll
    for (int k0 = 0; k0 < 4; ++k0) {
        a0[k0] = *(const v8bf*)(p0 + k0 * 32);
        a1[k0] = *(const v8bf*)(p1 + k0 * 32);
    }

#pragma unroll
    for (int nt = 0; nt < 8; ++nt) {
        const int boff = (nt * 16 + l16) * H + quad * 8;
        v4f ai0 = (v4f){0.f, 0.f, 0.f, 0.f}, ai1 = ai0;
        v4f ac0 = ai0, ac1 = ai0, ao0 = ai0, ao1 = ai0;
#pragma unroll
        for (int k0 = 0; k0 < 4; ++k0) {
            v8bf bi = *(const v8bf*)(Ui + boff + k0 * 32);
            v8bf bc = *(const v8bf*)(Uc + boff + k0 * 32);
            v8bf bo = *(const v8bf*)(Uo + boff + k0 * 32);
            ai0 = __builtin_amdgcn_mfma_f32_16x16x32_bf16(a0[k0], bi, ai0, 0, 0, 0);
            ai1 = __builtin_amdgcn_mfma_f32_16x16x32_bf16(a1[k0], bi, ai1, 0, 0, 0);
            ac0 = __builtin_amdgcn_mfma_f32_16x16x32_bf16(a0[k0], bc, ac0, 0, 0, 0);
            ac1 = __builtin_amdgcn_mfma_f32_16x16x32_bf16(a1[k0], bc, ac1, 0, 0, 0);
            ao0 = __builtin_amdgcn_mfma_f32_16x16x32_bf16(a0[k0], bo, ao0, 0, 0, 0);
            ao1 = __builtin_amdgcn_mfma_f32_16x16x32_bf16(a1[k0], bo, ao1, 0, 0, 0);
        }
        int n = nt * 16 + l16;
#pragma unroll
        for (int r = 0; r < 4; ++r) {
            int m0 = r0 + quad * 4 + r;
            if (m0 < M) {
                size_t idx = (size_t)m0 * H + n;
                float ig = fsigm((float)Xi[idx] + ai0[r]);
                float ct = ftanh((float)Xc[idx] + ac0[r]);
                float og = fsigm((float)Xo[idx] + ao0[r]);
                float c = ig * ct + sumfc[idx];
                out[idx] = og * ftanh(c);
                out[MH + idx] = c;
            }
            int m1 = m0 + 16;
            if (m1 < M) {
                size_t idx = (size_t)m1 * H + n;
                float ig = fsigm((float)Xi[idx] + ai1[r]);
                float ct = ftanh((float)Xc[idx] + ac1[r]);
                float og = fsigm((float)Xo[idx] + ao1[r]);
                float c = ig * ct + sumfc[idx];
                out[idx] = og * ftanh(c);
                out[MH + idx] = c;
            }
        }
    }
}

extern "C" void kernel_launch(void* const* d_in, const int* in_sizes, int n_in,
                              void* d_out, int out_size, void* d_ws, size_t ws_size,
                              hipStream_t stream) {
    const float* x_emb   = (const float*)d_in[0];
    const float* child_h = (const float*)d_in[1];
    const float* child_c = (const float*)d_in[2];
    const int*   ci      = (const int*)d_in[3];
    const int*   chi     = (const int*)d_in[4];
    const float* Wi_b = (const float*)d_in[15];
    const float* Wf_b = (const float*)d_in[16];
    const float* Wo_b = (const float*)d_in[17];
    const float* Wc_b = (const float*)d_in[18];
    const float* Wa_b = (const float*)d_in[19];
    const float* vw   = (const float*)d_in[20];

    const int M    = in_sizes[0] / H;
    const int L    = in_sizes[3];
    const int Mpad = (M + 127) & ~127;
    const int MH   = M * H;
    const int MH4  = MH / 4;

    char* p = (char*)d_ws;
    auto alloc = [&](size_t bytes) {
        char* r = p;
        p += (bytes + 255) & ~(size_t)255;
        return (void*)r;
    };
    size_t bfbytes = (size_t)Mpad * H * sizeof(__bf16);
    __bf16* xe16   = (__bf16*)alloc(bfbytes);
    __bf16* chA16  = (__bf16*)alloc(bfbytes);
    __bf16* P      = (__bf16*)alloc((size_t)Mpad * PSTRIDE * sizeof(__bf16));
    __bf16* hhat16 = (__bf16*)alloc(bfbytes);
    __bf16* Bx16   = (__bf16*)alloc(bfbytes);
    __bf16* Wfx16  = (__bf16*)alloc(bfbytes);
    __bf16* Xi16   = (__bf16*)alloc(bfbytes);
    __bf16* Xc16   = (__bf16*)alloc(bfbytes);
    __bf16* Xo16   = (__bf16*)alloc(bfbytes);
    __bf16* Wb     = (__bf16*)alloc(10 * 16384 * sizeof(__bf16));
    float* sumfc   = (float*)alloc((size_t)MH * 4);
    int*   payload = (int*)alloc((size_t)L * 4);
    int*   counts  = (int*)alloc((size_t)M * 4);
    int*   rowptr  = (int*)alloc((size_t)(M + 1) * 4);
    int*   cursor  = (int*)alloc((size_t)M * 4);
    int*   bsums   = (int*)alloc(1024 * 4);

    hipMemsetAsync(counts, 0, (size_t)M * 4, stream);

    WPtrs wp;
    for (int k = 0; k < 10; ++k) wp.w[k] = (const float*)d_in[5 + k];
    int prep_items = 40960 + MH4 + L;
    prep_k<<<(prep_items + 255) / 256, 256, 0, stream>>>(wp, Wb, x_emb, child_h, child_c,
                                                         xe16, chA16, P, ci, counts, MH4, L);

    const __bf16* Wi = Wb + 0 * 16384;
    const __bf16* Ui = Wb + 1 * 16384;
    const __bf16* Wf = Wb + 2 * 16384;
    const __bf16* Uf = Wb + 3 * 16384;
    const __bf16* Wo = Wb + 4 * 16384;
    const __bf16* Uo = Wb + 5 * 16384;
    const __bf16* Wc = Wb + 6 * 16384;
    const __bf16* Uc = Wb + 7 * 16384;
    const __bf16* Wa = Wb + 8 * 16384;
    const __bf16* Ua = Wb + 9 * 16384;

    MatBatch ba{};
    ba.m[0] = MatDesc{chA16, H, Wa, Wa_b,    P,     0, 3}; // Ah -> P interleaved slot 3
    ba.m[1] = MatDesc{xe16,  H, Ua, nullptr, Bx16,  H, -1};
    ba.m[2] = MatDesc{xe16,  H, Wf, Wf_b,    Wfx16, H, -1};
    ba.m[3] = MatDesc{chA16, H, Uf, nullptr, P,     0, 2}; // Ufh -> P interleaved slot 2
    ba.m[4] = MatDesc{xe16,  H, Wi, Wi_b,    Xi16,  H, -1};
    ba.m[5] = MatDesc{xe16,  H, Wc, Wc_b,    Xc16,  H, -1};
    ba.m[6] = MatDesc{xe16,  H, Wo, Wo_b,    Xo16,  H, -1};
    const int ntile = Mpad / 128;
    const int ntile8 = (ntile + 7) & ~7;
    gemm_batch<<<7 * ntile8, 256, 0, stream>>>(ba, M, ntile);

    int nb = (M + 1023) / 1024;
    scan_local<<<nb, 1024, 0, stream>>>(counts, rowptr, bsums, M);
    scan_fused<<<nb, 1024, 0, stream>>>(rowptr, cursor, bsums, counts, M, nb);

    scatter_k<<<(L + 255) / 256, 256, 0, stream>>>(ci, chi, cursor, payload, L);

    segment_fused<<<(M + 3) / 4, 128, 0, stream>>>(rowptr, payload, vw, Bx16, Wfx16, P,
                                                   hhat16, sumfc, M);

    gemm_final<<<Mpad / 128, 256, 0, stream>>>(hhat16, Ui, Uc, Uo, Xi16, Xc16, Xo16,
                                               sumfc, (float*)d_out, M, MH);
}

// Round 6
// 408.942 us; speedup vs baseline: 1.0475x; 1.0085x over previous
//
#include <hip/hip_runtime.h>
#include <cstdint>
#include <cstddef>

#define H 128
#define PSTRIDE 512   // packed row, interleaved by feature-quad: q*16 + [ch4|cc4|uf4|ah4]

typedef __bf16 v8bf __attribute__((ext_vector_type(8)));
typedef __bf16 v4bf __attribute__((ext_vector_type(4)));
typedef float  v4f  __attribute__((ext_vector_type(4)));

__device__ __forceinline__ float ftanh(float x) {
    return 1.f - 2.f / (1.f + __expf(2.f * x));
}
__device__ __forceinline__ float fsigm(float x) {
    return 1.f / (1.f + __expf(-x));
}

// 32-lane sum reduce: 4 DPP adds (VALU pipe, cheap) + 1 ds_swizzle xor16.
// All 32 lanes of each half end with the full sum. Halves are independent.
__device__ __forceinline__ float red32(float s) {
    int x;
    x = __builtin_amdgcn_update_dpp(0, __float_as_int(s), 0xB1, 0xF, 0xF, true);  // quad_perm [1,0,3,2] = xor1
    s += __int_as_float(x);
    x = __builtin_amdgcn_update_dpp(0, __float_as_int(s), 0x4E, 0xF, 0xF, true);  // quad_perm [2,3,0,1] = xor2
    s += __int_as_float(x);
    x = __builtin_amdgcn_update_dpp(0, __float_as_int(s), 0x141, 0xF, 0xF, true); // row_half_mirror (8-lane)
    s += __int_as_float(x);
    x = __builtin_amdgcn_update_dpp(0, __float_as_int(s), 0x140, 0xF, 0xF, true); // row_mirror (16-lane)
    s += __int_as_float(x);
    x = __builtin_amdgcn_ds_swizzle(__float_as_int(s), 0x401F);                   // xor16 within 32
    return s + __int_as_float(x);
}

struct MatDesc {
    const __bf16* A;    // bf16 A, stride lda
    int           lda;
    const __bf16* Wb;   // [128,128] bf16 [n][k]
    const float*  bias; // [128] or nullptr
    __bf16*       C;    // out base (contig if psec<0, else P-interleaved)
    int           ldc;
    int           psec; // -1 = contiguous; 2 = Ufh slot, 3 = Ah slot in P rows
};
struct MatBatch { MatDesc m[7]; };
struct WPtrs { const float* w[10]; };

// ---------------- prep: wconv (10 mats) + convert x/ch/cc + edge histogram ----------------
__global__ __launch_bounds__(256) void prep_k(WPtrs wp, __bf16* __restrict__ Wb,
                                              const float* __restrict__ x,
                                              const float* __restrict__ chh,
                                              const float* __restrict__ chc,
                                              __bf16* __restrict__ xe,
                                              __bf16* __restrict__ chA,
                                              __bf16* __restrict__ P,
                                              const int* __restrict__ ci,
                                              int* __restrict__ counts,
                                              int MH4, int L) {
    int tid = blockIdx.x * 256 + threadIdx.x;
    if (tid < 40960) {  // 10 * 4096 v4-chunks of weights
        int mat = tid >> 12;
        int off = (tid & 4095) << 2;
        v4f a = *(const v4f*)(wp.w[mat] + off);
        v4bf b;
#pragma unroll
        for (int k = 0; k < 4; ++k) b[k] = (__bf16)a[k];
        *(v4bf*)(Wb + mat * 16384 + off) = b;
        return;
    }
    int i = tid - 40960;
    if (i < MH4) {
        v4f a = ((const v4f*)x)[i];
        v4f b = ((const v4f*)chh)[i];
        v4f c = ((const v4f*)chc)[i];
        v4bf ab, bb, cb;
#pragma unroll
        for (int k = 0; k < 4; ++k) {
            ab[k] = (__bf16)a[k]; bb[k] = (__bf16)b[k]; cb[k] = (__bf16)c[k];
        }
        ((v4bf*)xe)[i] = ab;
        ((v4bf*)chA)[i] = bb;
        int m = i >> 5;
        int q = i & 31;
        __bf16* prow = P + (size_t)m * PSTRIDE + (q << 4);
        *(v4bf*)prow = bb;        // ch quad
        *(v4bf*)(prow + 4) = cb;  // cc quad
        return;
    }
    int l = i - MH4;
    if (l < L) atomicAdd(&counts[ci[l]], 1);
}

// ---------------- batched GEMM: 1-D grid, tile-grouped XCD swizzle ----------------
// blk -> (mat j, tile t) such that the 7 mats of tile t share XCD (blk%8) and a
// 56-block dispatch window: A-tile rows are read from HBM once, then L2-hit.
__global__ __launch_bounds__(256) void gemm_batch(MatBatch batch, int M, int ntile) {
    const int blk = blockIdx.x;
    const int g = blk / 56;
    const int w = blk % 56;
    const int j = w >> 3;             // mat 0..6
    const int t = (g << 3) | (w & 7); // tile
    if (t >= ntile) return;
    const MatDesc d = batch.m[j];
    __shared__ __bf16 wlds[H][H + 8];

    for (int tt = threadIdx.x; tt < 2048; tt += 256) {
        int n = tt >> 4;
        int k = (tt & 15) << 3;
        *(v8bf*)&wlds[n][k] = *(const v8bf*)(d.Wb + n * H + k);
    }
    __syncthreads();

    const int wave = threadIdx.x >> 6;
    const int lane = threadIdx.x & 63;
    const int quad = lane >> 4;
    const int l16  = lane & 15;
    const int r0   = t * 128 + wave * 32;

    int ra = r0 + l16;      if (ra > M - 1) ra = M - 1;
    int rb = r0 + 16 + l16; if (rb > M - 1) rb = M - 1;

    const __bf16* p0 = d.A + (size_t)ra * d.lda + quad * 8;
    const __bf16* p1 = d.A + (size_t)rb * d.lda + quad * 8;
    v8bf a0[4], a1[4];
#pragma unroll
    for (int k0 = 0; k0 < 4; ++k0) {
        a0[k0] = *(const v8bf*)(p0 + k0 * 32);
        a1[k0] = *(const v8bf*)(p1 + k0 * 32);
    }

    v4f acc0[8], acc1[8];
#pragma unroll
    for (int nt = 0; nt < 8; ++nt) {
        acc0[nt] = (v4f){0.f, 0.f, 0.f, 0.f};
        acc1[nt] = (v4f){0.f, 0.f, 0.f, 0.f};
    }

#pragma unroll
    for (int k0 = 0; k0 < 4; ++k0) {
#pragma unroll
        for (int nt = 0; nt < 8; ++nt) {
            v8bf b = *(const v8bf*)(&wlds[nt * 16 + l16][k0 * 32 + quad * 8]);
            acc0[nt] = __builtin_amdgcn_mfma_f32_16x16x32_bf16(a0[k0], b, acc0[nt], 0, 0, 0);
            acc1[nt] = __builtin_amdgcn_mfma_f32_16x16x32_bf16(a1[k0], b, acc1[nt], 0, 0, 0);
        }
    }

    if (d.psec >= 0) {
        // interleaved store into P rows: elem (m,n) -> m*512 + (n>>2)*16 + psec*4 + (n&3)
        const int so = d.psec << 2;
#pragma unroll
        for (int nt = 0; nt < 8; ++nt) {
            int n = nt * 16 + l16;
            float bia = d.bias ? d.bias[n] : 0.f;
            size_t col = ((size_t)(n >> 2) << 4) + so + (n & 3);
#pragma unroll
            for (int r = 0; r < 4; ++r) {
                int m0 = r0 + quad * 4 + r;
                int m1 = m0 + 16;
                if (m0 < M) d.C[(size_t)m0 * PSTRIDE + col] = (__bf16)(acc0[nt][r] + bia);
                if (m1 < M) d.C[(size_t)m1 * PSTRIDE + col] = (__bf16)(acc1[nt][r] + bia);
            }
        }
    } else {
#pragma unroll
        for (int nt = 0; nt < 8; ++nt) {
            int n = nt * 16 + l16;
            float bia = d.bias ? d.bias[n] : 0.f;
#pragma unroll
            for (int r = 0; r < 4; ++r) {
                int m0 = r0 + quad * 4 + r;
                int m1 = m0 + 16;
                if (m0 < M) d.C[(size_t)m0 * d.ldc + n] = (__bf16)(acc0[nt][r] + bia);
                if (m1 < M) d.C[(size_t)m1 * d.ldc + n] = (__bf16)(acc1[nt][r] + bia);
            }
        }
    }
}

// ---------------- scans ----------------
__global__ __launch_bounds__(1024) void scan_local(const int* __restrict__ counts,
                                                   int* __restrict__ excl,
                                                   int* __restrict__ bsums, int M) {
    __shared__ int s[1024];
    int tid = threadIdx.x;
    int idx = blockIdx.x * 1024 + tid;
    int v = (idx < M) ? counts[idx] : 0;
    s[tid] = v;
    __syncthreads();
    for (int off = 1; off < 1024; off <<= 1) {
        int t = (tid >= off) ? s[tid - off] : 0;
        __syncthreads();
        s[tid] += t;
        __syncthreads();
    }
    if (idx < M) excl[idx] = s[tid] - v;
    if (tid == 1023) bsums[blockIdx.x] = s[1023];
}

__global__ __launch_bounds__(1024) void scan_fused(int* __restrict__ rowptr,
                                                   int* __restrict__ cursor,
                                                   const int* __restrict__ bsums,
                                                   const int* __restrict__ counts,
                                                   int M, int nb) {
    __shared__ int s[1024];
    int t = threadIdx.x, b = blockIdx.x;
    int v = (t < nb) ? bsums[t] : 0;
    s[t] = v;
    __syncthreads();
    for (int off = 1; off < 1024; off <<= 1) {
        int tt = (t >= off) ? s[t - off] : 0;
        __syncthreads();
        s[t] += tt;
        __syncthreads();
    }
    int boff = (b == 0) ? 0 : s[b - 1];
    int idx = b * 1024 + t;
    if (idx < M) {
        int val = rowptr[idx] + boff;
        rowptr[idx] = val;
        cursor[idx] = val;
        if (idx == M - 1) rowptr[M] = val + counts[M - 1];
    }
}

// ---------------- scatter: CSR payload = child index ----------------
__global__ __launch_bounds__(256) void scatter_k(const int* __restrict__ ci,
                                                 const int* __restrict__ chi,
                                                 int* __restrict__ cursor,
                                                 int* __restrict__ payload, int L) {
    int l = blockIdx.x * 256 + threadIdx.x;
    if (l < L) {
        int pos = atomicAdd(&cursor[ci[l]], 1);
        payload[pos] = chi[l];
    }
}

// ---------------- fused attention + segment reduce, SINGLE PASS ----------------
// 32 lanes/segment, 4 feats/lane. Per edge: ONE 32B interleaved P read (2 x b128),
// score reduce via 4 DPP adds + 1 ds_swizzle (short serial chain).
__global__ __launch_bounds__(128) void segment_fused(const int* __restrict__ rowptr,
                                                     const int* __restrict__ payload,
                                                     const float* __restrict__ vw,
                                                     const __bf16* __restrict__ Bx,
                                                     const __bf16* __restrict__ Wfx,
                                                     const __bf16* __restrict__ P,
                                                     __bf16* __restrict__ hhat,
                                                     float* __restrict__ sumfc, int M) {
    const int wl   = threadIdx.x & 63;
    const int half = wl & 32;
    const int l32  = wl & 31;
    const int m = blockIdx.x * 4 + (threadIdx.x >> 5);
    if (m >= M) return;
    const int start = rowptr[m];
    const int deg   = rowptr[m + 1] - start;
    const int h   = l32 << 2;
    const int q16 = l32 << 4;

    v4bf bx4 = *(const v4bf*)(Bx + (m << 7) + h);
    v4bf wf4 = *(const v4bf*)(Wfx + (m << 7) + h);
    v4f  vv  = *(const v4f*)(vw + h);
    float bxf[4], wff[4];
#pragma unroll
    for (int k = 0; k < 4; ++k) { bxf[k] = (float)bx4[k]; wff[k] = (float)wf4[k]; }

    // batch payload loads (1 per lane per 32 edges)
    int pl0 = (l32 < deg) ? payload[start + l32] : 0;
    int pl1 = (32 + l32 < deg) ? payload[start + 32 + l32] : 0;

    float denom = 0.f;
    float acch[4] = {0.f, 0.f, 0.f, 0.f};
    float accf[4] = {0.f, 0.f, 0.f, 0.f};

    const int jcap = deg < 64 ? deg : 64;
    for (int j = 0; j < jcap; ++j) {
        int cj = __shfl((j & 32) ? pl1 : pl0, half | (j & 31), 64);
        const __bf16* pb = P + ((size_t)cj << 9) + q16;
        v8bf x0 = *(const v8bf*)pb;        // ch0-3 | cc0-3
        v8bf x1 = *(const v8bf*)(pb + 8);  // uf0-3 | ah0-3
        float s = 0.f;
#pragma unroll
        for (int k = 0; k < 4; ++k) s += ftanh((float)x1[4 + k] + bxf[k]) * vv[k];
        s = red32(s);
        float ex = __expf(s);
        denom += ex;
#pragma unroll
        for (int k = 0; k < 4; ++k) {
            acch[k] = fmaf(ex, (float)x0[k], acch[k]);
            accf[k] += fsigm(wff[k] + (float)x1[k]) * (float)x0[4 + k];
        }
    }
    // rare tail (deg > 64)
    for (int j = 64; j < deg; ++j) {
        int cj = payload[start + j];
        const __bf16* pb = P + ((size_t)cj << 9) + q16;
        v8bf x0 = *(const v8bf*)pb;
        v8bf x1 = *(const v8bf*)(pb + 8);
        float s = 0.f;
#pragma unroll
        for (int k = 0; k < 4; ++k) s += ftanh((float)x1[4 + k] + bxf[k]) * vv[k];
        s = red32(s);
        float ex = __expf(s);
        denom += ex;
#pragma unroll
        for (int k = 0; k < 4; ++k) {
            acch[k] = fmaf(ex, (float)x0[k], acch[k]);
            accf[k] += fsigm(wff[k] + (float)x1[k]) * (float)x0[4 + k];
        }
    }

    float inv = 1.f / (denom + 1e-9f);
    v4bf hb;
    v4f sf;
#pragma unroll
    for (int k = 0; k < 4; ++k) { hb[k] = (__bf16)(acch[k] * inv); sf[k] = accf[k]; }
    *(v4bf*)(hhat + (size_t)m * H + h) = hb;
    *(v4f*)(sumfc + (size_t)m * H + h) = sf;
}

// ---------------- fused gemm2 (hhat @ {Ui,Uc,Uo}) + LSTM epilogue, NO LDS ----------------
// Weights (96 KB total) are L2/L3-resident. gridDim.y=4 splits the 8 column-tiles
// (2 per block): 4x the waves fixes the grid-limited 17% occupancy seen in profiling.
__global__ __launch_bounds__(256) void gemm_final(const __bf16* __restrict__ hhat,
                                                  const __bf16* __restrict__ Ui,
                                                  const __bf16* __restrict__ Uc,
                                                  const __bf16* __restrict__ Uo,
                                                  const __bf16* __restrict__ Xi,
                                                  const __bf16* __restrict__ Xc,
                                                  const __bf16* __restrict__ Xo,
                                                  const float* __restrict__ sumfc,
                                                  float* __restrict__ out, int M, int MH) {
    const int wave = threadIdx.x >> 6;
    const int lane = threadIdx.x & 63;
    const int quad = lane >> 4;
    const int l16  = lane & 15;
    const int r0   = blockIdx.x * 128 + wave * 32;
    const int nt0  = blockIdx.y * 2;

    // hhat is Mpad-padded workspace; rows >= M are garbage but masked at store
    const __bf16* p0 = hhat + (size_t)(r0 + l16) * H + quad * 8;
    const __bf16* p1 = hhat + (size_t)(r0 + 16 + l16) * H + quad * 8;
    v8bf a0[4], a1[4];
#pragma unroll
    for (int k0 = 0; k0 < 4; ++k0) {
        a0[k0] = *(const v8bf*)(p0 + k0 * 32);
        a1[k0] = *(const v8bf*)(p1 + k0 * 32);
    }

#pragma unroll
    for (int ntl = 0; ntl < 2; ++ntl) {
        const int nt = nt0 + ntl;
        const int boff = (nt * 16 + l16) * H + quad * 8;
        v4f ai0 = (v4f){0.f, 0.f, 0.f, 0.f}, ai1 = ai0;
        v4f ac0 = ai0, ac1 = ai0, ao0 = ai0, ao1 = ai0;
#pragma unroll
        for (int k0 = 0; k0 < 4; ++k0) {
            v8bf bi = *(const v8bf*)(Ui + boff + k0 * 32);
            v8bf bc = *(const v8bf*)(Uc + boff + k0 * 32);
            v8bf bo = *(const v8bf*)(Uo + boff + k0 * 32);
            ai0 = __builtin_amdgcn_mfma_f32_16x16x32_bf16(a0[k0], bi, ai0, 0, 0, 0);
            ai1 = __builtin_amdgcn_mfma_f32_16x16x32_bf16(a1[k0], bi, ai1, 0, 0, 0);
            ac0 = __builtin_amdgcn_mfma_f32_16x16x32_bf16(a0[k0], bc, ac0, 0, 0, 0);
            ac1 = __builtin_amdgcn_mfma_f32_16x16x32_bf16(a1[k0], bc, ac1, 0, 0, 0);
            ao0 = __builtin_amdgcn_mfma_f32_16x16x32_bf16(a0[k0], bo, ao0, 0, 0, 0);
            ao1 = __builtin_amdgcn_mfma_f32_16x16x32_bf16(a1[k0], bo, ao1, 0, 0, 0);
        }
        int n = nt * 16 + l16;
#pragma unroll
        for (int r = 0; r < 4; ++r) {
            int m0 = r0 + quad * 4 + r;
            if (m0 < M) {
                size_t idx = (size_t)m0 * H + n;
                float ig = fsigm((float)Xi[idx] + ai0[r]);
                float ct = ftanh((float)Xc[idx] + ac0[r]);
                float og = fsigm((float)Xo[idx] + ao0[r]);
                float c = ig * ct + sumfc[idx];
                out[idx] = og * ftanh(c);
                out[MH + idx] = c;
            }
            int m1 = m0 + 16;
            if (m1 < M) {
                size_t idx = (size_t)m1 * H + n;
                float ig = fsigm((float)Xi[idx] + ai1[r]);
                float ct = ftanh((float)Xc[idx] + ac1[r]);
                float og = fsigm((float)Xo[idx] + ao1[r]);
                float c = ig * ct + sumfc[idx];
                out[idx] = og * ftanh(c);
                out[MH + idx] = c;
            }
        }
    }
}

extern "C" void kernel_launch(void* const* d_in, const int* in_sizes, int n_in,
                              void* d_out, int out_size, void* d_ws, size_t ws_size,
                              hipStream_t stream) {
    const float* x_emb   = (const float*)d_in[0];
    const float* child_h = (const float*)d_in[1];
    const float* child_c = (const float*)d_in[2];
    const int*   ci      = (const int*)d_in[3];
    const int*   chi     = (const int*)d_in[4];
    const float* Wi_b = (const float*)d_in[15];
    const float* Wf_b = (const float*)d_in[16];
    const float* Wo_b = (const float*)d_in[17];
    const float* Wc_b = (const float*)d_in[18];
    const float* Wa_b = (const float*)d_in[19];
    const float* vw   = (const float*)d_in[20];

    const int M    = in_sizes[0] / H;
    const int L    = in_sizes[3];
    const int Mpad = (M + 127) & ~127;
    const int MH   = M * H;
    const int MH4  = MH / 4;

    char* p = (char*)d_ws;
    auto alloc = [&](size_t bytes) {
        char* r = p;
        p += (bytes + 255) & ~(size_t)255;
        return (void*)r;
    };
    size_t bfbytes = (size_t)Mpad * H * sizeof(__bf16);
    __bf16* xe16   = (__bf16*)alloc(bfbytes);
    __bf16* chA16  = (__bf16*)alloc(bfbytes);
    __bf16* P      = (__bf16*)alloc((size_t)Mpad * PSTRIDE * sizeof(__bf16));
    __bf16* hhat16 = (__bf16*)alloc(bfbytes);
    __bf16* Bx16   = (__bf16*)alloc(bfbytes);
    __bf16* Wfx16  = (__bf16*)alloc(bfbytes);
    __bf16* Xi16   = (__bf16*)alloc(bfbytes);
    __bf16* Xc16   = (__bf16*)alloc(bfbytes);
    __bf16* Xo16   = (__bf16*)alloc(bfbytes);
    __bf16* Wb     = (__bf16*)alloc(10 * 16384 * sizeof(__bf16));
    float* sumfc   = (float*)alloc((size_t)MH * 4);
    int*   payload = (int*)alloc((size_t)L * 4);
    int*   counts  = (int*)alloc((size_t)M * 4);
    int*   rowptr  = (int*)alloc((size_t)(M + 1) * 4);
    int*   cursor  = (int*)alloc((size_t)M * 4);
    int*   bsums   = (int*)alloc(1024 * 4);

    hipMemsetAsync(counts, 0, (size_t)M * 4, stream);

    WPtrs wp;
    for (int k = 0; k < 10; ++k) wp.w[k] = (const float*)d_in[5 + k];
    int prep_items = 40960 + MH4 + L;
    prep_k<<<(prep_items + 255) / 256, 256, 0, stream>>>(wp, Wb, x_emb, child_h, child_c,
                                                         xe16, chA16, P, ci, counts, MH4, L);

    const __bf16* Wi = Wb + 0 * 16384;
    const __bf16* Ui = Wb + 1 * 16384;
    const __bf16* Wf = Wb + 2 * 16384;
    const __bf16* Uf = Wb + 3 * 16384;
    const __bf16* Wo = Wb + 4 * 16384;
    const __bf16* Uo = Wb + 5 * 16384;
    const __bf16* Wc = Wb + 6 * 16384;
    const __bf16* Uc = Wb + 7 * 16384;
    const __bf16* Wa = Wb + 8 * 16384;
    const __bf16* Ua = Wb + 9 * 16384;

    MatBatch ba{};
    ba.m[0] = MatDesc{chA16, H, Wa, Wa_b,    P,     0, 3}; // Ah -> P interleaved slot 3
    ba.m[1] = MatDesc{xe16,  H, Ua, nullptr, Bx16,  H, -1};
    ba.m[2] = MatDesc{xe16,  H, Wf, Wf_b,    Wfx16, H, -1};
    ba.m[3] = MatDesc{chA16, H, Uf, nullptr, P,     0, 2}; // Ufh -> P interleaved slot 2
    ba.m[4] = MatDesc{xe16,  H, Wi, Wi_b,    Xi16,  H, -1};
    ba.m[5] = MatDesc{xe16,  H, Wc, Wc_b,    Xc16,  H, -1};
    ba.m[6] = MatDesc{xe16,  H, Wo, Wo_b,    Xo16,  H, -1};
    const int ntile = Mpad / 128;
    const int ntile8 = (ntile + 7) & ~7;
    gemm_batch<<<7 * ntile8, 256, 0, stream>>>(ba, M, ntile);

    int nb = (M + 1023) / 1024;
    scan_local<<<nb, 1024, 0, stream>>>(counts, rowptr, bsums, M);
    scan_fused<<<nb, 1024, 0, stream>>>(rowptr, cursor, bsums, counts, M, nb);

    scatter_k<<<(L + 255) / 256, 256, 0, stream>>>(ci, chi, cursor, payload, L);

    segment_fused<<<(M + 3) / 4, 128, 0, stream>>>(rowptr, payload, vw, Bx16, Wfx16, P,
                                                   hhat16, sumfc, M);

    gemm_final<<<dim3(Mpad / 128, 4), 256, 0, stream>>>(hhat16, Ui, Uc, Uo, Xi16, Xc16, Xo16,
                                                        sumfc, (float*)d_out, M, MH);
}